// Round 19
// baseline (120.462 us; speedup 1.0000x reference)
//
#include <hip/hip_runtime.h>

#define NP_   16384
#define NQ_   8192
#define NB_   2
#define K_    16
#define QPB   8            // queries per block (2 quads; each quad = 2 waves)
#define TPB   256
#define HALF  (NP_/2)      // 8192 points per wave
#define GPH   (HALF/64)    // 128 group-iterations
#define CBUF  80           // per-(wave,query) append buffer (15 carry + 64 max)

#define IDX_OFF 0
#define RS_OFF  (NB_*NQ_*K_)        // 262144
#define RS_N    (NB_*NQ_+1)         // 16385
#define DST_OFF (RS_OFF + RS_N)     // 278529

typedef unsigned long long ull;

__device__ __forceinline__ int mbcnt64(ull m) {
    return __builtin_amdgcn_mbcnt_hi((unsigned)(m >> 32),
           __builtin_amdgcn_mbcnt_lo((unsigned)m, 0));
}

__global__ __launch_bounds__(TPB, 4) void knn_kernel(const float* __restrict__ pts,
                                                     const float* __restrict__ qrs,
                                                     float* __restrict__ out)
{
    // Validated exact-match formula (R6):
    //   sq, sp : forward sum, separate mul/add rounds
    //   ip     : forward FMA chain  fma(z,qz, fma(y,qy, round(x*qx)))
    //   d      : fmaf(-2, ip, sq+sp)
    // d computed ONCE, buffered, sorted by lex (d, idx) -> exact stable.
    #pragma clang fp contract(off)

    __shared__ float2 buf[16][CBUF];     // 10KB: 4 waves x 4 query-slots
    __shared__ float2 mg[2][64];         // 1KB: half-1 lists per quad

    const int tid  = threadIdx.x;
    const int lane = tid & 63;
    const int s    = lane & 15;               // rank this lane owns
    const int g    = lane >> 4;               // query slot within wave (0..3)
    const int wv   = tid >> 6;                // wave 0..3
    const int qgrp = wv >> 1;                 // quad id in block
    const int half = wv & 1;                  // 0: [0,8192)  1: [8192,16384)
    const int bq   = tid >> 4;                // wave-local buffer id (= wv*4+g)
    const int qb   = wv << 2;                 // wave's buffer base

    const int q0   = blockIdx.x * QPB + (qgrp << 2);
    const int gq   = q0 + g;                  // lane's own query
    const int batch = gq >> 13;
    const int gofs  = batch * NP_;
    const float* pb = pts + (size_t)gofs * 3;

    float qxv[4], qyv[4], qzv[4], sqv[4];
    #pragma unroll
    for (int qi = 0; qi < 4; ++qi) {
        const float* qp = qrs + (size_t)(q0 + qi) * 3;
        qxv[qi] = qp[0]; qyv[qi] = qp[1]; qzv[qi] = qp[2];
        sqv[qi] = qxv[qi]*qxv[qi] + qyv[qi]*qyv[qi] + qzv[qi]*qzv[qi]; // fwd, no FMA
    }

    const float INF = __int_as_float(0x7f800000);
    float hd = INF; int hi = 0x7fffffff;      // distributed top-16: rank-s of own query
    float th0 = INF, th1 = INF, th2 = INF, th3 = INF;
    int cnt0 = 0, cnt1 = 0, cnt2 = 0, cnt3 = 0;

    // drain all buffered entries into the distributed lists (wave-uniform)
    auto drain = [&]() {
        int cmax = max(max(cnt0, cnt1), max(cnt2, cnt3));
        int mycnt = (g==0) ? cnt0 : (g==1) ? cnt1 : (g==2) ? cnt2 : cnt3;
        for (int r = 0; r < cmax; r += K_) {
            float nd = INF; int ni = 0x7fffffff;
            int pos = r + s;
            if (pos < mycnt) {
                float2 e = buf[bq][pos];
                nd = e.x; ni = __float_as_int(e.y);
            }
            // bitonic sort-16 ascending by (d, idx) within each 16-lane group
            #pragma unroll
            for (int m = 2; m <= 16; m <<= 1) {
                #pragma unroll
                for (int j = m >> 1; j > 0; j >>= 1) {
                    float od = __shfl_xor(nd, j);
                    int   oi = __shfl_xor(ni, j);
                    bool pl = (od < nd) || (od == nd && oi < ni);
                    bool keepmin = ((s & j) == 0) == ((s & m) == 0);
                    if (keepmin == pl) { nd = od; ni = oi; }
                }
            }
            // Batcher halver vs sorted list: keep min(L[s], N[15-s])
            float od = __shfl_xor(nd, 15);
            int   oi = __shfl_xor(ni, 15);
            bool pl = (od < hd) || (od == hd && oi < hi);
            if (pl) { hd = od; hi = oi; }
            // bitonic cleanup (4 stages, ascending)
            #pragma unroll
            for (int j = 8; j > 0; j >>= 1) {
                float od2 = __shfl_xor(hd, j);
                int   oi2 = __shfl_xor(hi, j);
                bool pl2 = (od2 < hd) || (od2 == hd && oi2 < hi);
                if (((s & j) == 0) == pl2) { hd = od2; hi = oi2; }
            }
        }
        cnt0 = cnt1 = cnt2 = cnt3 = 0;
        th0 = __shfl(hd, 15, 64);             // exact 16th-best per query (this half)
        th1 = __shfl(hd, 31, 64);
        th2 = __shfl(hd, 47, 64);
        th3 = __shfl(hd, 63, 64);
    };

    const int pbase0 = half * HALF;
    #pragma unroll 2
    for (int gi = 0; gi < GPH; ++gi) {
        int pid = pbase0 + (gi << 6) + lane;  // 64 distinct points, coalesced
        const float* pp = pb + (size_t)pid * 3;
        float x = pp[0], y = pp[1], z = pp[2];
        float sp = x*x + y*y + z*z;           // fwd, no FMA
        float ip0 = fmaf(z, qzv[0], fmaf(y, qyv[0], __fmul_rn(x, qxv[0])));
        float ip1 = fmaf(z, qzv[1], fmaf(y, qyv[1], __fmul_rn(x, qxv[1])));
        float ip2 = fmaf(z, qzv[2], fmaf(y, qyv[2], __fmul_rn(x, qxv[2])));
        float ip3 = fmaf(z, qzv[3], fmaf(y, qyv[3], __fmul_rn(x, qxv[3])));
        float d0 = fmaf(-2.0f, ip0, sqv[0] + sp);
        float d1 = fmaf(-2.0f, ip1, sqv[1] + sp);
        float d2 = fmaf(-2.0f, ip2, sqv[2] + sp);
        float d3 = fmaf(-2.0f, ip3, sqv[3] + sp);
        ull m0 = __ballot(d0 <= th0);         // <= : tie-safe superset filter
        ull m1 = __ballot(d1 <= th1);
        ull m2 = __ballot(d2 <= th2);
        ull m3 = __ballot(d3 <= th3);
        if (m0 | m1 | m2 | m3) {              // uniform scalar skip
            const float fpid = __int_as_float(pid);
            if (m0) {                         // append: slot = cnt + mbcnt(mask)
                int sl = cnt0 + mbcnt64(m0);
                if (d0 <= th0) buf[qb+0][sl] = make_float2(d0, fpid);
                cnt0 += (int)__popcll(m0);
            }
            if (m1) {
                int sl = cnt1 + mbcnt64(m1);
                if (d1 <= th1) buf[qb+1][sl] = make_float2(d1, fpid);
                cnt1 += (int)__popcll(m1);
            }
            if (m2) {
                int sl = cnt2 + mbcnt64(m2);
                if (d2 <= th2) buf[qb+2][sl] = make_float2(d2, fpid);
                cnt2 += (int)__popcll(m2);
            }
            if (m3) {
                int sl = cnt3 + mbcnt64(m3);
                if (d3 <= th3) buf[qb+3][sl] = make_float2(d3, fpid);
                cnt3 += (int)__popcll(m3);
            }
            if ((cnt0 | cnt1 | cnt2 | cnt3) >= K_) drain();
        }
    }

    drain();                                  // flush leftovers (<16 per query)

    // ---- merge the two halves (half-0 indices always < half-1: stable) ----
    if (half == 1) mg[qgrp][lane] = make_float2(hd, __int_as_float(hi));
    __syncthreads();
    if (half == 0) {
        // Batcher halver: min(A[s], B[15-s]) = smallest-16 set
        float2 o = mg[qgrp][(lane & 48) | (15 - s)];
        float bd = o.x; int bi = __float_as_int(o.y);
        bool takeB = (bd < hd) || (bd == hd && bi < hi);
        float md = takeB ? bd : hd;
        int   mi = takeB ? bi : hi;
        // bitonic cleanup: 4 stages, ascending by (d, idx)
        #pragma unroll
        for (int off = 8; off >= 1; off >>= 1) {
            float od = __shfl_xor(md, off, 16);
            int   oi = __shfl_xor(mi, off, 16);
            bool pl = (od < md) || (od == md && oi < mi);
            bool keepmin = (s & off) == 0;
            if (keepmin == pl) { md = od; mi = oi; }
        }
        out[IDX_OFF + gq*K_ + s] = (float)(mi + gofs);
        out[DST_OFF + gq*K_ + s] = fmaxf(md, 0.0f);
    }

    // row_splits = arange(16385) * 16, written as float (exact)
    int gt = blockIdx.x * TPB + tid;
    if (gt < RS_N) out[RS_OFF + gt] = (float)(gt * K_);
}

extern "C" void kernel_launch(void* const* d_in, const int* in_sizes, int n_in,
                              void* d_out, int out_size, void* d_ws, size_t ws_size,
                              hipStream_t stream)
{
    const float* pts = (const float*)d_in[0];
    const float* qrs = (const float*)d_in[1];
    float* out = (float*)d_out;
    (void)in_sizes; (void)n_in; (void)out_size; (void)d_ws; (void)ws_size;

    dim3 grid(NB_ * NQ_ / QPB);   // 2048 blocks = 8 blocks/CU
    dim3 block(TPB);              // 256 threads (4 waves)
    knn_kernel<<<grid, block, 0, stream>>>(pts, qrs, out);
}

// Round 20
// 119.089 us; speedup vs baseline: 1.0115x; 1.0115x over previous
//
#include <hip/hip_runtime.h>

#define NP_   16384
#define NQ_   8192
#define NB_   2
#define K_    16
#define QPB   16           // queries per block (4 per wave x 4 waves)
#define TPB   256
#define GPT   (NP_/64)     // 256 group-iterations (64 points each)
#define CBUF  96           // per-query append buffer (31 carry + 64 max)

#define IDX_OFF 0
#define RS_OFF  (NB_*NQ_*K_)        // 262144
#define RS_N    (NB_*NQ_+1)         // 16385
#define DST_OFF (RS_OFF + RS_N)     // 278529

typedef unsigned long long ull;
typedef float f32x2 __attribute__((ext_vector_type(2)));

__device__ __forceinline__ int mbcnt64(ull m) {
    return __builtin_amdgcn_mbcnt_hi((unsigned)(m >> 32),
           __builtin_amdgcn_mbcnt_lo((unsigned)m, 0));
}

__global__ __launch_bounds__(TPB, 4) void knn_kernel(const float* __restrict__ pts,
                                                     const float* __restrict__ qrs,
                                                     float* __restrict__ out)
{
    // Validated exact-match formula (R6):
    //   sq, sp : forward sum, separate mul/add rounds
    //   ip     : forward FMA chain  fma(z,qz, fma(y,qy, round(x*qx)))
    //   d      : fmaf(-2, ip, sq+sp)
    // Packed (v_pk_*) components are IEEE-identical per lane-component:
    // same ops, same order, same roundings -> bit-exact vs scalar chain.
    #pragma clang fp contract(off)

    __shared__ float2 buf[QPB][CBUF];    // 12KB append buffers

    const int tid  = threadIdx.x;
    const int lane = tid & 63;
    const int s    = lane & 15;               // rank this lane owns
    const int g    = lane >> 4;               // query slot within wave (0..3)
    const int bq   = tid >> 4;                // block-level id of OWN query
    const int gq   = blockIdx.x * QPB + bq;
    const int batch = gq >> 13;
    const int gofs  = batch * NP_;
    const float* pb = pts + (size_t)gofs * 3;
    const int qb   = (tid >> 6) << 2;         // wave's first block-level query

    float qxv[4], qyv[4], qzv[4], sqv[4];
    #pragma unroll
    for (int qi = 0; qi < 4; ++qi) {
        const float* qp = qrs + (size_t)(blockIdx.x * QPB + qb + qi) * 3;
        qxv[qi] = qp[0]; qyv[qi] = qp[1]; qzv[qi] = qp[2];
        sqv[qi] = qxv[qi]*qxv[qi] + qyv[qi]*qyv[qi] + qzv[qi]*qzv[qi]; // fwd, no FMA
    }
    const f32x2 qx01 = {qxv[0], qxv[1]}, qx23 = {qxv[2], qxv[3]};
    const f32x2 qy01 = {qyv[0], qyv[1]}, qy23 = {qyv[2], qyv[3]};
    const f32x2 qz01 = {qzv[0], qzv[1]}, qz23 = {qzv[2], qzv[3]};
    const f32x2 sq01 = {sqv[0], sqv[1]}, sq23 = {sqv[2], sqv[3]};
    const f32x2 n2   = {-2.0f, -2.0f};

    const float INF = __int_as_float(0x7f800000);
    float hd = INF; int hi = 0x7fffffff;      // distributed top-16: rank-s of own query
    float th0 = INF, th1 = INF, th2 = INF, th3 = INF;
    int cnt0 = 0, cnt1 = 0, cnt2 = 0, cnt3 = 0;

    // drain all buffered entries into the distributed lists (wave-uniform)
    auto drain = [&]() {
        int cmax = max(max(cnt0, cnt1), max(cnt2, cnt3));
        int mycnt = (g==0) ? cnt0 : (g==1) ? cnt1 : (g==2) ? cnt2 : cnt3;
        for (int r = 0; r < cmax; r += K_) {
            float nd = INF; int ni = 0x7fffffff;
            int pos = r + s;
            if (pos < mycnt) {
                float2 e = buf[bq][pos];
                nd = e.x; ni = __float_as_int(e.y);
            }
            // bitonic sort-16 ascending by (d, idx) within each 16-lane group
            #pragma unroll
            for (int m = 2; m <= 16; m <<= 1) {
                #pragma unroll
                for (int j = m >> 1; j > 0; j >>= 1) {
                    float od = __shfl_xor(nd, j);
                    int   oi = __shfl_xor(ni, j);
                    bool pl = (od < nd) || (od == nd && oi < ni);
                    bool keepmin = ((s & j) == 0) == ((s & m) == 0);
                    if (keepmin == pl) { nd = od; ni = oi; }
                }
            }
            // Batcher halver vs sorted list: keep min(L[s], N[15-s])
            float od = __shfl_xor(nd, 15);
            int   oi = __shfl_xor(ni, 15);
            bool pl = (od < hd) || (od == hd && oi < hi);
            if (pl) { hd = od; hi = oi; }
            // bitonic cleanup (4 stages, ascending)
            #pragma unroll
            for (int j = 8; j > 0; j >>= 1) {
                float od2 = __shfl_xor(hd, j);
                int   oi2 = __shfl_xor(hi, j);
                bool pl2 = (od2 < hd) || (od2 == hd && oi2 < hi);
                if (((s & j) == 0) == pl2) { hd = od2; hi = oi2; }
            }
        }
        cnt0 = cnt1 = cnt2 = cnt3 = 0;
        th0 = __shfl(hd, 15, 64);             // exact 16th-best per query
        th1 = __shfl(hd, 31, 64);
        th2 = __shfl(hd, 47, 64);
        th3 = __shfl(hd, 63, 64);
    };

    #pragma unroll 2
    for (int gi = 0; gi < GPT; ++gi) {
        int pid = (gi << 6) + lane;           // 64 distinct points, coalesced
        const float* pp = pb + (size_t)pid * 3;
        float x = pp[0], y = pp[1], z = pp[2];
        float sp = x*x + y*y + z*z;           // fwd, no FMA
        f32x2 x2 = {x, x}, y2 = {y, y}, z2 = {z, z}, sps = {sp, sp};
        f32x2 ip01 = __builtin_elementwise_fma(z2, qz01,
                     __builtin_elementwise_fma(y2, qy01, x2*qx01));
        f32x2 ip23 = __builtin_elementwise_fma(z2, qz23,
                     __builtin_elementwise_fma(y2, qy23, x2*qx23));
        f32x2 d01 = __builtin_elementwise_fma(n2, ip01, sq01 + sps);
        f32x2 d23 = __builtin_elementwise_fma(n2, ip23, sq23 + sps);
        float d0 = d01.x, d1 = d01.y, d2 = d23.x, d3 = d23.y;
        ull m0 = __ballot(d0 <= th0);         // <= : tie-safe superset filter
        ull m1 = __ballot(d1 <= th1);
        ull m2 = __ballot(d2 <= th2);
        ull m3 = __ballot(d3 <= th3);
        if (m0 | m1 | m2 | m3) {              // uniform scalar skip
            const float fpid = __int_as_float(pid);
            if (m0) {                         // append: slot = cnt + mbcnt(mask)
                int sl = cnt0 + mbcnt64(m0);
                if (d0 <= th0) buf[qb+0][sl] = make_float2(d0, fpid);
                cnt0 += (int)__popcll(m0);
            }
            if (m1) {
                int sl = cnt1 + mbcnt64(m1);
                if (d1 <= th1) buf[qb+1][sl] = make_float2(d1, fpid);
                cnt1 += (int)__popcll(m1);
            }
            if (m2) {
                int sl = cnt2 + mbcnt64(m2);
                if (d2 <= th2) buf[qb+2][sl] = make_float2(d2, fpid);
                cnt2 += (int)__popcll(m2);
            }
            if (m3) {
                int sl = cnt3 + mbcnt64(m3);
                if (d3 <= th3) buf[qb+3][sl] = make_float2(d3, fpid);
                cnt3 += (int)__popcll(m3);
            }
            if ((cnt0 | cnt1 | cnt2 | cnt3) >= 32) drain();
        }
    }

    drain();                                  // flush leftovers

    // output: lane s holds rank-s of its query
    out[IDX_OFF + gq*K_ + s] = (float)(hi + gofs);
    out[DST_OFF + gq*K_ + s] = fmaxf(hd, 0.0f);

    // row_splits = arange(16385) * 16, written as float (exact)
    int gt = blockIdx.x * TPB + tid;
    if (gt < RS_N) out[RS_OFF + gt] = (float)(gt * K_);
}

extern "C" void kernel_launch(void* const* d_in, const int* in_sizes, int n_in,
                              void* d_out, int out_size, void* d_ws, size_t ws_size,
                              hipStream_t stream)
{
    const float* pts = (const float*)d_in[0];
    const float* qrs = (const float*)d_in[1];
    float* out = (float*)d_out;
    (void)in_sizes; (void)n_in; (void)out_size; (void)d_ws; (void)ws_size;

    dim3 grid(NB_ * NQ_ / QPB);   // 1024 blocks
    dim3 block(TPB);              // 256 threads
    knn_kernel<<<grid, block, 0, stream>>>(pts, qrs, out);
}

// Round 21
// 114.004 us; speedup vs baseline: 1.0566x; 1.0446x over previous
//
#include <hip/hip_runtime.h>

#define NP_   16384
#define NQ_   8192
#define NB_   2
#define K_    16
#define QPB   16           // queries per block (4 per wave x 4 waves)
#define TPB   256
#define TILE  1024         // points per LDS tile (16KB)
#define NTILES (NP_/TILE)  // 16
#define GPT   (TILE/64)    // 16 group-iterations per tile
#define CBUF  80           // per-query append buffer (15 carry + 64/iter max)

#define IDX_OFF 0
#define RS_OFF  (NB_*NQ_*K_)        // 262144
#define RS_N    (NB_*NQ_+1)         // 16385
#define DST_OFF (RS_OFF + RS_N)     // 278529

typedef unsigned long long ull;
typedef float f32x2 __attribute__((ext_vector_type(2)));

__device__ __forceinline__ int mbcnt64(ull m) {
    return __builtin_amdgcn_mbcnt_hi((unsigned)(m >> 32),
           __builtin_amdgcn_mbcnt_lo((unsigned)m, 0));
}

__global__ __launch_bounds__(TPB, 4) void knn_kernel(const float* __restrict__ pts,
                                                     const float* __restrict__ qrs,
                                                     float* __restrict__ out)
{
    // Validated exact-match formula (R6):
    //   sq, sp : forward sum, separate mul/add rounds
    //   ip     : forward FMA chain  fma(z,qz, fma(y,qy, round(x*qx)))
    //   d      : fmaf(-2, ip, sq+sp)
    // Packed components are IEEE-identical per component (same ops, same
    // order, same roundings) -> bit-exact vs the scalar chain.
    #pragma clang fp contract(off)

    __shared__ float4 tile[TILE];        // 16KB
    __shared__ float2 buf[QPB][CBUF];    // 10KB append buffers

    const int tid  = threadIdx.x;
    const int lane = tid & 63;
    const int s    = lane & 15;               // rank this lane owns
    const int g    = lane >> 4;               // query slot within wave (0..3)
    const int bq   = tid >> 4;                // block-level id of OWN query
    const int gq   = blockIdx.x * QPB + bq;
    const int batch = gq >> 13;
    const int gofs  = batch * NP_;
    const float* pb = pts + (size_t)gofs * 3;
    const int qb   = (tid >> 6) << 2;         // wave's first block-level query

    float qxv[4], qyv[4], qzv[4], sqv[4];
    #pragma unroll
    for (int qi = 0; qi < 4; ++qi) {
        const float* qp = qrs + (size_t)(blockIdx.x * QPB + qb + qi) * 3;
        qxv[qi] = qp[0]; qyv[qi] = qp[1]; qzv[qi] = qp[2];
        sqv[qi] = qxv[qi]*qxv[qi] + qyv[qi]*qyv[qi] + qzv[qi]*qzv[qi]; // fwd, no FMA
    }
    const f32x2 qx01 = {qxv[0], qxv[1]}, qx23 = {qxv[2], qxv[3]};
    const f32x2 qy01 = {qyv[0], qyv[1]}, qy23 = {qyv[2], qyv[3]};
    const f32x2 qz01 = {qzv[0], qzv[1]}, qz23 = {qzv[2], qzv[3]};
    const f32x2 sq01 = {sqv[0], sqv[1]}, sq23 = {sqv[2], sqv[3]};
    const f32x2 n2   = {-2.0f, -2.0f};

    const float INF = __int_as_float(0x7f800000);
    float hd = INF; int hi = 0x7fffffff;      // distributed top-16: rank-s of own query
    float th0 = INF, th1 = INF, th2 = INF, th3 = INF;
    int cnt0 = 0, cnt1 = 0, cnt2 = 0, cnt3 = 0;

    // drain all buffered entries into the distributed lists (wave-uniform)
    auto drain = [&]() {
        int cmax = max(max(cnt0, cnt1), max(cnt2, cnt3));
        int mycnt = (g==0) ? cnt0 : (g==1) ? cnt1 : (g==2) ? cnt2 : cnt3;
        for (int r = 0; r < cmax; r += K_) {
            float nd = INF; int ni = 0x7fffffff;
            int pos = r + s;
            if (pos < mycnt) {
                float2 e = buf[bq][pos];
                nd = e.x; ni = __float_as_int(e.y);
            }
            // bitonic sort-16 ascending by (d, idx) within each 16-lane group
            #pragma unroll
            for (int m = 2; m <= 16; m <<= 1) {
                #pragma unroll
                for (int j = m >> 1; j > 0; j >>= 1) {
                    float od = __shfl_xor(nd, j);
                    int   oi = __shfl_xor(ni, j);
                    bool pl = (od < nd) || (od == nd && oi < ni);
                    bool keepmin = ((s & j) == 0) == ((s & m) == 0);
                    if (keepmin == pl) { nd = od; ni = oi; }
                }
            }
            // Batcher halver vs sorted list: keep min(L[s], N[15-s])
            float od = __shfl_xor(nd, 15);
            int   oi = __shfl_xor(ni, 15);
            bool pl = (od < hd) || (od == hd && oi < hi);
            if (pl) { hd = od; hi = oi; }
            // bitonic cleanup (4 stages, ascending)
            #pragma unroll
            for (int j = 8; j > 0; j >>= 1) {
                float od2 = __shfl_xor(hd, j);
                int   oi2 = __shfl_xor(hi, j);
                bool pl2 = (od2 < hd) || (od2 == hd && oi2 < hi);
                if (((s & j) == 0) == pl2) { hd = od2; hi = oi2; }
            }
        }
        cnt0 = cnt1 = cnt2 = cnt3 = 0;
        th0 = __shfl(hd, 15, 64);             // exact 16th-best per query
        th1 = __shfl(hd, 31, 64);
        th2 = __shfl(hd, 47, 64);
        th3 = __shfl(hd, 63, 64);
    };

    for (int t = 0; t < NTILES; ++t) {
        __syncthreads();
        #pragma unroll
        for (int k = 0; k < TILE/TPB; ++k) {
            int lp = tid + k*TPB;
            int gp = t*TILE + lp;
            float x = pb[gp*3+0], y = pb[gp*3+1], z = pb[gp*3+2];
            float sp = x*x + y*y + z*z;       // fwd, no FMA
            tile[lp] = make_float4(x, y, z, sp);
        }
        __syncthreads();

        #pragma unroll 4
        for (int gi = 0; gi < GPT; ++gi) {
            float4 p = tile[gi*64 + lane];    // 64 distinct points, ds_read_b128
            f32x2 x2 = {p.x, p.x}, y2 = {p.y, p.y}, z2 = {p.z, p.z};
            f32x2 sps = {p.w, p.w};
            f32x2 ip01 = __builtin_elementwise_fma(z2, qz01,
                         __builtin_elementwise_fma(y2, qy01, x2*qx01));
            f32x2 ip23 = __builtin_elementwise_fma(z2, qz23,
                         __builtin_elementwise_fma(y2, qy23, x2*qx23));
            f32x2 d01 = __builtin_elementwise_fma(n2, ip01, sq01 + sps);
            f32x2 d23 = __builtin_elementwise_fma(n2, ip23, sq23 + sps);
            float d0 = d01.x, d1 = d01.y, d2 = d23.x, d3 = d23.y;
            ull m0 = __ballot(d0 <= th0);     // <= : tie-safe superset filter
            ull m1 = __ballot(d1 <= th1);
            ull m2 = __ballot(d2 <= th2);
            ull m3 = __ballot(d3 <= th3);
            if (m0 | m1 | m2 | m3) {          // uniform scalar skip
                const float fpid = __int_as_float(t*TILE + gi*64 + lane);
                if (m0) {                     // append: slot = cnt + mbcnt(mask)
                    int sl = cnt0 + mbcnt64(m0);
                    if (d0 <= th0) buf[qb+0][sl] = make_float2(d0, fpid);
                    cnt0 += (int)__popcll(m0);
                }
                if (m1) {
                    int sl = cnt1 + mbcnt64(m1);
                    if (d1 <= th1) buf[qb+1][sl] = make_float2(d1, fpid);
                    cnt1 += (int)__popcll(m1);
                }
                if (m2) {
                    int sl = cnt2 + mbcnt64(m2);
                    if (d2 <= th2) buf[qb+2][sl] = make_float2(d2, fpid);
                    cnt2 += (int)__popcll(m2);
                }
                if (m3) {
                    int sl = cnt3 + mbcnt64(m3);
                    if (d3 <= th3) buf[qb+3][sl] = make_float2(d3, fpid);
                    cnt3 += (int)__popcll(m3);
                }
                if ((cnt0 | cnt1 | cnt2 | cnt3) >= K_) drain();
            }
        }
    }

    drain();                                  // flush leftovers (<16 per query)

    // output: lane s holds rank-s of its query
    out[IDX_OFF + gq*K_ + s] = (float)(hi + gofs);
    out[DST_OFF + gq*K_ + s] = fmaxf(hd, 0.0f);

    // row_splits = arange(16385) * 16, written as float (exact)
    int gt = blockIdx.x * TPB + tid;
    if (gt < RS_N) out[RS_OFF + gt] = (float)(gt * K_);
}

extern "C" void kernel_launch(void* const* d_in, const int* in_sizes, int n_in,
                              void* d_out, int out_size, void* d_ws, size_t ws_size,
                              hipStream_t stream)
{
    const float* pts = (const float*)d_in[0];
    const float* qrs = (const float*)d_in[1];
    float* out = (float*)d_out;
    (void)in_sizes; (void)n_in; (void)out_size; (void)d_ws; (void)ws_size;

    dim3 grid(NB_ * NQ_ / QPB);   // 1024 blocks
    dim3 block(TPB);              // 256 threads
    knn_kernel<<<grid, block, 0, stream>>>(pts, qrs, out);
}